// Round 10
// baseline (343.656 us; speedup 1.0000x reference)
//
#include <hip/hip_runtime.h>
#include <hip/hip_bf16.h>
#include <math.h>

#define BB 128
#define NN 12000
#define NIN 4000
#define NFN 7000
#define NOMIC 3600
#define FC 56000
#define EE 57000
#define LAT 100

typedef __hip_bfloat16 bf16;
typedef __attribute__((ext_vector_type(8))) short bf16x8;
typedef __attribute__((ext_vector_type(4))) float f32x4;

__device__ __forceinline__ ushort f2bf(float f) {
  bf16 h = __float2bfloat16(f);
  return *(ushort*)&h;
}
__device__ __forceinline__ float bf2f(ushort u) {
  bf16 h = *(bf16*)&u;
  return __bfloat162float(h);
}

// ---------------- transpose x (B,N) -> xT (N,B) ----------------
__global__ void k_transpose(const float* __restrict__ x, float* __restrict__ xT) {
  __shared__ float t[32][33];
  int n0 = blockIdx.x * 32, b0 = blockIdx.y * 32;
  int tx = threadIdx.x, ty = threadIdx.y;
#pragma unroll
  for (int s = 0; s < 4; s++) {
    int b = b0 + ty + s * 8;
    int n = n0 + tx;
    t[ty + s * 8][tx] = x[b * NN + n];
  }
  __syncthreads();
#pragma unroll
  for (int s = 0; s < 4; s++) {
    int n = n0 + ty + s * 8;
    int b = b0 + tx;
    xT[n * BB + b] = t[tx][ty + s * 8];
  }
}

// ---------------- AE layer 1: h[k*128+b], split-K (80 chunks of 45) ----------------
__global__ void k_ae1(const float* __restrict__ xT, const float* __restrict__ W1,
                      float* __restrict__ h) {
  int b = threadIdx.x;
  int j0 = blockIdx.x * 4;
  int k0 = blockIdx.y * 45;
  float acc0 = 0.f, acc1 = 0.f, acc2 = 0.f, acc3 = 0.f;
  const float* xp = &xT[(size_t)k0 * BB + b];
  const float* wp = &W1[(size_t)k0 * LAT + j0];
#pragma unroll 5
  for (int kk = 0; kk < 45; kk++) {
    float xv = xp[kk * BB];
    float4 w = *(const float4*)(wp + kk * LAT);
    acc0 += xv * w.x; acc1 += xv * w.y; acc2 += xv * w.z; acc3 += xv * w.w;
  }
  atomicAdd(&h[(j0 + 0) * BB + b], acc0);
  atomicAdd(&h[(j0 + 1) * BB + b], acc1);
  atomicAdd(&h[(j0 + 2) * BB + b], acc2);
  atomicAdd(&h[(j0 + 3) * BB + b], acc3);
}

// ---------------- W2 fp32 -> bf16 in MFMA A-frag-ready layout -------------------------
// w2m[((J*4+S)*64+lane)*8 + i] = W2[k][j], j = J*16+(lane&15), k = S*32+(lane>>4)*8+i,
// zero-padded for k >= 100. One wave-load per (J,S) A-frag in k_ae2.
__global__ void k_w2m(const float* __restrict__ W2, ushort* __restrict__ w2m) {
  int gid = blockIdx.x * 256 + threadIdx.x;  // 896,000 = 3500 J * 4 S * 64 lanes
  int lane = gid & 63;
  int JS = gid >> 6;
  int S = JS & 3, J = JS >> 2;
  int j = J * 16 + (lane & 15);
  int k0 = S * 32 + (lane >> 4) * 8;
  union { ushort u[8]; uint4 v; } p;
#pragma unroll
  for (int i = 0; i < 8; i++) {
    int k = k0 + i;
    p.u[i] = (k < LAT) ? f2bf(W2[(size_t)k * FC + j]) : (ushort)0;
  }
  *(uint4*)&w2m[(size_t)gid * 8] = p.v;
}

// ---------------- elu(h+b_ae1) -> hbf in MFMA B-frag-ready layout ---------------------
// hbf[((S*8+t)*64+lane)*8 + i] = elu(h[k][b]), b = t*16+(lane&15), k = S*32+(lane>>4)*8+i,
// zero-padded k >= 100. 16384 bf16 = 32 KB total.
__global__ void k_hstage(const float* __restrict__ h, const float* __restrict__ b_ae1,
                         ushort* __restrict__ hbf) {
  int gid = blockIdx.x * 256 + threadIdx.x;  // 2048 groups of 8
  int lane = gid & 63;
  int St = gid >> 6;  // 0..31
  int S = St >> 3, t = St & 7;
  int b = t * 16 + (lane & 15);
  int k0 = S * 32 + (lane >> 4) * 8;
  union { ushort u[8]; uint4 v; } p;
#pragma unroll
  for (int i = 0; i < 8; i++) {
    int k = k0 + i;
    if (k < LAT) {
      float v = h[k * BB + b] + b_ae1[k];
      p.u[i] = f2bf(v > 0.f ? v : expm1f(v));
    } else {
      p.u[i] = 0;
    }
  }
  *(uint4*)&hbf[(size_t)gid * 8] = p.v;
}

// ---------------- build xeT (bf16) from xT / src ----------------
__global__ void k_build_xe(const float* __restrict__ xT, const int* __restrict__ src,
                           ushort* __restrict__ xeT) {
  int idx = blockIdx.x * 256 + threadIdx.x;
  if (idx >= EE * BB) return;
  int e = idx >> 7, b = idx & 127;
  int s = src[e];
  xeT[idx] = (s < NOMIC) ? f2bf(0.f) : f2bf(xT[s * BB + b]);
}

// ---------------- map[e] = fe-position i (else -1, pre-set by memset 0xFF) ----------------
__global__ void k_map(const int* __restrict__ w3_cols, int* __restrict__ map, int n_fe) {
  int i = blockIdx.x * 256 + threadIdx.x;
  if (i < n_fe) map[w3_cols[i * 8]] = i;
}

// ---------------- AE layer 2 GEMM via MFMA: zT[f][b][c](bf16) = h @ W2 + b2, + LN sums --
// 875 blocks x 256 thr (4 waves). Wave = 16 j x 128 b, K=128 (padded).
// Per wave: 4 A-frag dwordx4 (coalesced) + 8 btiles x (4 ds_read_b128 + 4 MFMA).
__launch_bounds__(256)
__global__ void k_ae2(const ushort* __restrict__ hbf, const ushort* __restrict__ w2m,
                      const float* __restrict__ b_ae2, ushort* __restrict__ zT,
                      float* __restrict__ red) {
  __shared__ __align__(16) ushort hB[16384];  // 32 KB B-frag-ready h
  __shared__ float lred[256];
  int tid = threadIdx.x;
  lred[tid] = 0.f;
  for (int i = tid * 8; i < 16384; i += 256 * 8)
    *(uint4*)&hB[i] = *(const uint4*)&hbf[i];
  __syncthreads();

  int wave = tid >> 6, lane = tid & 63;
  int J = blockIdx.x * 4 + wave;  // j-tile (3500 total)
  int j0 = J * 16;
  int q = lane >> 4, n = lane & 15;

  // A-frags: W2^T rows j0..j0+15, all 4 k-steps
  bf16x8 a[4];
#pragma unroll
  for (int S = 0; S < 4; S++)
    a[S] = *(const bf16x8*)&w2m[(size_t)((J * 4 + S) * 64 + lane) * 8];

  // bias for this lane's 4 j (j = j0 + q*4 + r) — wave-broadcast float4
  float4 bias = *(const float4*)&b_ae2[j0 + q * 4];
  int jb = j0 + q * 4;       // j of reg 0; 4 consecutive j stay within one f-octet
  int f = jb >> 3, c0 = jb & 7;

#pragma unroll
  for (int t = 0; t < 8; t++) {
    f32x4 acc = (f32x4){0.f, 0.f, 0.f, 0.f};
#pragma unroll
    for (int S = 0; S < 4; S++) {
      bf16x8 bfr = *(const bf16x8*)&hB[((S * 8 + t) * 64 + lane) * 8];
      acc = __builtin_amdgcn_mfma_f32_16x16x32_bf16(a[S], bfr, acc, 0, 0, 0);
    }
    int b = t * 16 + n;
    float v0 = acc[0] + bias.x, v1 = acc[1] + bias.y;
    float v2 = acc[2] + bias.z, v3 = acc[3] + bias.w;
    ushort4 pk;
    pk.x = f2bf(v0); pk.y = f2bf(v1); pk.z = f2bf(v2); pk.w = f2bf(v3);
    *(ushort4*)&zT[(size_t)f * 1024 + b * 8 + c0] = pk;
    float s = v0 + v1 + v2 + v3;
    float qq = v0 * v0 + v1 * v1 + v2 * v2 + v3 * v3;
    atomicAdd(&lred[b * 2], s);
    atomicAdd(&lred[b * 2 + 1], qq);
  }
  __syncthreads();
  atomicAdd(&red[tid], lred[tid]);
}

// ---------------- layer part 1: hfc = elu(s * groupLN(8x8 matmul(xe) + b1)) -------------
// 4 f per block x 64 lanes x 2 b per thread (two independent chains).
__launch_bounds__(256)
__global__ void k_layer1(const ushort* __restrict__ xeT, const float* __restrict__ w1l,
                         const float* __restrict__ b1l, const uint4* __restrict__ zT4,
                         const float* __restrict__ red, uint4* __restrict__ hfcT4) {
  __shared__ __align__(16) float wsm[4][64];
  __shared__ float bsm[4][8];
  int tid = threadIdx.x;
  int fs = tid >> 6;   // 0..3
  int lane = tid & 63;
  int f = blockIdx.x * 4 + fs;
  wsm[tid >> 6][tid & 63] = w1l[blockIdx.x * 256 + tid];
  if (tid < 32) bsm[tid >> 3][tid & 7] = b1l[blockIdx.x * 32 + tid];
  __syncthreads();

#pragma unroll
  for (int half = 0; half < 2; half++) {
    int b = lane + half * 64;
    float mu_ln = red[b * 2] * (1.f / FC);
    float var_ln = red[b * 2 + 1] * (1.f / FC) - mu_ln * mu_ln;
    float isg_ln = rsqrtf(var_ln + 1e-5f);

    float xv[8];
#pragma unroll
    for (int k = 0; k < 8; k++) xv[k] = bf2f(xeT[(f * 8 + k) * BB + b]);
    float acc[8];
#pragma unroll
    for (int c = 0; c < 8; c++) acc[c] = bsm[fs][c];
#pragma unroll
    for (int k = 0; k < 8; k++) {
      const float4* wp = (const float4*)&wsm[fs][k * 8];
      float4 w0 = wp[0], w1 = wp[1];
      acc[0] += xv[k] * w0.x; acc[1] += xv[k] * w0.y;
      acc[2] += xv[k] * w0.z; acc[3] += xv[k] * w0.w;
      acc[4] += xv[k] * w1.x; acc[5] += xv[k] * w1.y;
      acc[6] += xv[k] * w1.z; acc[7] += xv[k] * w1.w;
    }
    float mu = 0.f;
#pragma unroll
    for (int c = 0; c < 8; c++) mu += acc[c];
    mu *= 0.125f;
    float var = 0.f;
#pragma unroll
    for (int c = 0; c < 8; c++) { float d = acc[c] - mu; var += d * d; }
    var *= 0.125f;
    float sc = rsqrtf(var + 1e-5f);

    union { ushort u[8]; uint4 v; } zu;
    zu.v = zT4[(size_t)f * BB + b];
    union { ushort u[8]; uint4 v; } pk;
#pragma unroll
    for (int c = 0; c < 8; c++) {
      float v = (acc[c] - mu) * sc;
      float sv = 1.f / (1.f + expf(-(bf2f(zu.u[c]) - mu_ln) * isg_ln));
      float hv = sv * v;
      hv = hv > 0.f ? hv : expm1f(hv);
      pk.u[c] = f2bf(hv);
    }
    hfcT4[(size_t)f * BB + b] = pk.v;
  }
}

// ---------------- layer part 2: xe = (fe? dot8(hfc[src], w3) : 0) + b3 + xe ----------------
__launch_bounds__(256)
__global__ void k_layer2(const uint4* __restrict__ hfcT4, const float* __restrict__ w3l,
                         const float* __restrict__ b3l, const int* __restrict__ map,
                         const int* __restrict__ src, ushort* __restrict__ xeT) {
  __shared__ float wsm[4][8];
  int tid = threadIdx.x;
  int es = tid >> 6;   // 0..3
  int lane = tid & 63;
  int e = blockIdx.x * 4 + es;
  if (tid < 32) {
    int q = tid;
    int ee = blockIdx.x * 4 + (q >> 3);
    int ii = map[ee];
    wsm[q >> 3][q & 7] = (ii >= 0) ? w3l[ii * 8 + (q & 7)] : 0.f;
  }
  __syncthreads();
  int i = map[e];
  int g = src[e] - NIN;
  float be = b3l[e];
#pragma unroll
  for (int half = 0; half < 2; half++) {
    int b = lane + half * 64;
    float rv = be + bf2f(xeT[e * BB + b]);
    if (i >= 0) {
      union { ushort u[8]; uint4 v; } hv;
      hv.v = hfcT4[(size_t)g * BB + b];
      float a = 0.f;
#pragma unroll
      for (int c = 0; c < 8; c++) a += bf2f(hv.u[c]) * wsm[es][c];
      rv += a;
    }
    xeT[e * BB + b] = f2bf(rv);
  }
}

// ---------------- output: out[b, 11000+j] = xe[b, 56000+j] / 4 ----------------
__global__ void k_out(const ushort* __restrict__ xeT, float* __restrict__ out) {
  __shared__ float t[32][33];
  int j0 = blockIdx.x * 32, b0 = blockIdx.y * 32;
  int tx = threadIdx.x, ty = threadIdx.y;
#pragma unroll
  for (int s2 = 0; s2 < 4; s2++) {
    int j = j0 + ty + s2 * 8;
    if (j < 1000) t[ty + s2 * 8][tx] = bf2f(xeT[(FC + j) * BB + b0 + tx]);
  }
  __syncthreads();
#pragma unroll
  for (int s2 = 0; s2 < 4; s2++) {
    int b = b0 + ty + s2 * 8;
    int j = j0 + tx;
    if (j < 1000) out[b * NN + 11000 + j] = t[tx][ty + s2 * 8] * 0.25f;
  }
}

extern "C" void kernel_launch(void* const* d_in, const int* in_sizes, int n_in,
                              void* d_out, int out_size, void* d_ws, size_t ws_size,
                              hipStream_t stream) {
  const float* x = (const float*)d_in[0];
  const float* W_ae1 = (const float*)d_in[1];
  const float* b_ae1 = (const float*)d_in[2];
  const float* W_ae2 = (const float*)d_in[3];
  const float* b_ae2 = (const float*)d_in[4];
  const float* w1_vals = (const float*)d_in[5];
  const float* b1 = (const float*)d_in[6];
  const float* w3_vals = (const float*)d_in[7];
  const float* b3 = (const float*)d_in[8];
  const int* src = (const int*)d_in[9];
  const int* w3_cols = (const int*)d_in[14];

  int nnz3 = in_sizes[13];
  int n_fe = nnz3 / 8;

  // Workspace (f32 slot offsets); all uint4 regions 16B-aligned.
  float* W = (float*)d_ws;
  float* h_raw = W + 0;                   // 12,800  [k*128+b]
  float* red = W + 12800;                 // 256
  ushort* hbf = (ushort*)(W + 13056);     // 16,384 bf16 = 8,192 -> ends 21,248
  int* map = (int*)(W + 21248);           // 57,000 ints -> ends 78,248
  float* xT = W + 78400;                  // 1,536,000 -> ends 1,614,400
  ushort* xeT = (ushort*)(W + 1614400);   // 3,648,000 -> ends 5,262,400
  uint4* zT4 = (uint4*)(W + 5262400);     // 3,584,000 -> ends 8,846,400
  uint4* hfcT4 = (uint4*)(W + 8846400);   // 3,584,000 -> ends 12,430,400
  ushort* w2m = (ushort*)(W + 12430400);  // 7,168,000 bf16 = 3,584,000 -> ends 16,014,400

  hipMemsetAsync(h_raw, 0, 13056 * sizeof(float), stream);  // h_raw + red
  hipMemsetAsync(map, 0xFF, EE * sizeof(int), stream);
  hipMemsetAsync(d_out, 0, (size_t)out_size * sizeof(float), stream);

  k_transpose<<<dim3(NN / 32, BB / 32), dim3(32, 8), 0, stream>>>(x, xT);
  k_w2m<<<3500, 256, 0, stream>>>(W_ae2, w2m);
  k_ae1<<<dim3(25, 80), 128, 0, stream>>>(xT, W_ae1, h_raw);
  k_build_xe<<<(EE * BB) / 256, 256, 0, stream>>>(xT, src, xeT);
  k_map<<<(n_fe + 255) / 256, 256, 0, stream>>>(w3_cols, map, n_fe);
  k_hstage<<<8, 256, 0, stream>>>(h_raw, b_ae1, hbf);
  k_ae2<<<875, 256, 0, stream>>>(hbf, w2m, b_ae2, (ushort*)zT4, red);
  for (int l = 0; l < 4; l++) {
    k_layer1<<<NFN / 4, 256, 0, stream>>>(xeT, w1_vals + (size_t)l * 448000,
                                          b1 + (size_t)l * FC, zT4, red, hfcT4);
    k_layer2<<<EE / 4, 256, 0, stream>>>(hfcT4, w3_vals + (size_t)l * nnz3,
                                         b3 + (size_t)l * EE, map, src, xeT);
  }
  k_out<<<dim3(32, 4), dim3(32, 8), 0, stream>>>(xeT, (float*)d_out);
}

// Round 11
// 324.884 us; speedup vs baseline: 1.0578x; 1.0578x over previous
//
#include <hip/hip_runtime.h>
#include <hip/hip_bf16.h>
#include <math.h>

#define BB 128
#define NN 12000
#define NIN 4000
#define NFN 7000
#define NOMIC 3600
#define FC 56000
#define EE 57000
#define LAT 100

typedef __hip_bfloat16 bf16;
typedef __attribute__((ext_vector_type(8))) short bf16x8;
typedef __attribute__((ext_vector_type(4))) float f32x4;

__device__ __forceinline__ ushort f2bf(float f) {
  bf16 h = __float2bfloat16(f);
  return *(ushort*)&h;
}
__device__ __forceinline__ float bf2f(ushort u) {
  bf16 h = *(bf16*)&u;
  return __bfloat162float(h);
}

// ---------------- transpose x (B,N) -> xT (N,B) ----------------
__global__ void k_transpose(const float* __restrict__ x, float* __restrict__ xT) {
  __shared__ float t[32][33];
  int n0 = blockIdx.x * 32, b0 = blockIdx.y * 32;
  int tx = threadIdx.x, ty = threadIdx.y;
#pragma unroll
  for (int s = 0; s < 4; s++) {
    int b = b0 + ty + s * 8;
    int n = n0 + tx;
    t[ty + s * 8][tx] = x[b * NN + n];
  }
  __syncthreads();
#pragma unroll
  for (int s = 0; s < 4; s++) {
    int n = n0 + ty + s * 8;
    int b = b0 + tx;
    xT[n * BB + b] = t[tx][ty + s * 8];
  }
}

// ---------------- AE layer 1: h[k*128+b], split-K (80 chunks of 45) ----------------
__global__ void k_ae1(const float* __restrict__ xT, const float* __restrict__ W1,
                      float* __restrict__ h) {
  int b = threadIdx.x;
  int j0 = blockIdx.x * 4;
  int k0 = blockIdx.y * 45;
  float acc0 = 0.f, acc1 = 0.f, acc2 = 0.f, acc3 = 0.f;
  const float* xp = &xT[(size_t)k0 * BB + b];
  const float* wp = &W1[(size_t)k0 * LAT + j0];
#pragma unroll 5
  for (int kk = 0; kk < 45; kk++) {
    float xv = xp[kk * BB];
    float4 w = *(const float4*)(wp + kk * LAT);
    acc0 += xv * w.x; acc1 += xv * w.y; acc2 += xv * w.z; acc3 += xv * w.w;
  }
  atomicAdd(&h[(j0 + 0) * BB + b], acc0);
  atomicAdd(&h[(j0 + 1) * BB + b], acc1);
  atomicAdd(&h[(j0 + 2) * BB + b], acc2);
  atomicAdd(&h[(j0 + 3) * BB + b], acc3);
}

// ---------------- W2 fp32 -> bf16 in MFMA A-frag-ready layout -------------------------
__global__ void k_w2m(const float* __restrict__ W2, ushort* __restrict__ w2m) {
  int gid = blockIdx.x * 256 + threadIdx.x;  // 896,000 = 3500 J * 4 S * 64 lanes
  int lane = gid & 63;
  int JS = gid >> 6;
  int S = JS & 3, J = JS >> 2;
  int j = J * 16 + (lane & 15);
  int k0 = S * 32 + (lane >> 4) * 8;
  union { ushort u[8]; uint4 v; } p;
#pragma unroll
  for (int i = 0; i < 8; i++) {
    int k = k0 + i;
    p.u[i] = (k < LAT) ? f2bf(W2[(size_t)k * FC + j]) : (ushort)0;
  }
  *(uint4*)&w2m[(size_t)gid * 8] = p.v;
}

// ---------------- elu(h+b_ae1) -> hbf in MFMA B-frag-ready layout ---------------------
__global__ void k_hstage(const float* __restrict__ h, const float* __restrict__ b_ae1,
                         ushort* __restrict__ hbf) {
  int gid = blockIdx.x * 256 + threadIdx.x;  // 2048 groups of 8
  int lane = gid & 63;
  int St = gid >> 6;  // 0..31
  int S = St >> 3, t = St & 7;
  int b = t * 16 + (lane & 15);
  int k0 = S * 32 + (lane >> 4) * 8;
  union { ushort u[8]; uint4 v; } p;
#pragma unroll
  for (int i = 0; i < 8; i++) {
    int k = k0 + i;
    if (k < LAT) {
      float v = h[k * BB + b] + b_ae1[k];
      p.u[i] = f2bf(v > 0.f ? v : expm1f(v));
    } else {
      p.u[i] = 0;
    }
  }
  *(uint4*)&hbf[(size_t)gid * 8] = p.v;
}

// ---------------- build edge state: xeF[f][b][c] uint4 (fc) + xeO (out edges) ---------
__global__ void k_build_xe(const float* __restrict__ xT, const int* __restrict__ src,
                           uint4* __restrict__ xeF, ushort* __restrict__ xeO) {
  int gid = blockIdx.x * 256 + threadIdx.x;  // 4000 blocks: 896000 fc + 128000 out
  if (gid < NFN * BB) {
    int f = gid >> 7, b = gid & 127;
    union { ushort u[8]; uint4 v; } p;
#pragma unroll
    for (int c = 0; c < 8; c++) {
      int s = src[f * 8 + c];
      p.u[c] = (s < NOMIC) ? (ushort)f2bf(0.f) : f2bf(xT[s * BB + b]);
    }
    xeF[(size_t)f * BB + b] = p.v;
  } else {
    int idx = gid - NFN * BB;  // 0..128000
    int eo = idx >> 7, b = idx & 127;
    int s = src[FC + eo];
    xeO[idx] = (s < NOMIC) ? (ushort)f2bf(0.f) : f2bf(xT[s * BB + b]);
  }
}

// ---------------- map[e] = fe-position i (else -1, pre-set by memset 0xFF) ----------------
__global__ void k_map(const int* __restrict__ w3_cols, int* __restrict__ map, int n_fe) {
  int i = blockIdx.x * 256 + threadIdx.x;
  if (i < n_fe) map[w3_cols[i * 8]] = i;
}

// ---------------- AE layer 2 GEMM via MFMA: zT[f][b][c](bf16) = h @ W2 + b2, + LN sums --
__launch_bounds__(256)
__global__ void k_ae2(const ushort* __restrict__ hbf, const ushort* __restrict__ w2m,
                      const float* __restrict__ b_ae2, ushort* __restrict__ zT,
                      float* __restrict__ red) {
  __shared__ __align__(16) ushort hB[16384];  // 32 KB B-frag-ready h
  __shared__ float lred[256];
  int tid = threadIdx.x;
  lred[tid] = 0.f;
  for (int i = tid * 8; i < 16384; i += 256 * 8)
    *(uint4*)&hB[i] = *(const uint4*)&hbf[i];
  __syncthreads();

  int wave = tid >> 6, lane = tid & 63;
  int J = blockIdx.x * 4 + wave;  // j-tile (3500 total)
  int j0 = J * 16;
  int q = lane >> 4, n = lane & 15;

  bf16x8 a[4];
#pragma unroll
  for (int S = 0; S < 4; S++)
    a[S] = *(const bf16x8*)&w2m[(size_t)((J * 4 + S) * 64 + lane) * 8];

  float4 bias = *(const float4*)&b_ae2[j0 + q * 4];
  int jb = j0 + q * 4;
  int f = jb >> 3, c0 = jb & 7;

#pragma unroll
  for (int t = 0; t < 8; t++) {
    f32x4 acc = (f32x4){0.f, 0.f, 0.f, 0.f};
#pragma unroll
    for (int S = 0; S < 4; S++) {
      bf16x8 bfr = *(const bf16x8*)&hB[((S * 8 + t) * 64 + lane) * 8];
      acc = __builtin_amdgcn_mfma_f32_16x16x32_bf16(a[S], bfr, acc, 0, 0, 0);
    }
    int b = t * 16 + n;
    float v0 = acc[0] + bias.x, v1 = acc[1] + bias.y;
    float v2 = acc[2] + bias.z, v3 = acc[3] + bias.w;
    ushort4 pk;
    pk.x = f2bf(v0); pk.y = f2bf(v1); pk.z = f2bf(v2); pk.w = f2bf(v3);
    *(ushort4*)&zT[(size_t)f * 1024 + b * 8 + c0] = pk;
    float s = v0 + v1 + v2 + v3;
    float qq = v0 * v0 + v1 * v1 + v2 * v2 + v3 * v3;
    atomicAdd(&lred[b * 2], s);
    atomicAdd(&lred[b * 2 + 1], qq);
  }
  __syncthreads();
  atomicAdd(&red[tid], lred[tid]);
}

// ---------------- layer part 1: hfc = elu(s * groupLN(8x8 matmul(xe) + b1)) -------------
// xeF in [f][b][c] layout: ONE uint4 read per (f,b) instead of 8 scalar u16 loads.
__launch_bounds__(256)
__global__ void k_layer1(const uint4* __restrict__ xeF, const float* __restrict__ w1l,
                         const float* __restrict__ b1l, const uint4* __restrict__ zT4,
                         const float* __restrict__ red, uint4* __restrict__ hfcT4) {
  __shared__ __align__(16) float wsm[4][64];
  __shared__ float bsm[4][8];
  int tid = threadIdx.x;
  int fs = tid >> 6;   // 0..3
  int lane = tid & 63;
  int f = blockIdx.x * 4 + fs;
  wsm[tid >> 6][tid & 63] = w1l[blockIdx.x * 256 + tid];
  if (tid < 32) bsm[tid >> 3][tid & 7] = b1l[blockIdx.x * 32 + tid];
  __syncthreads();

#pragma unroll
  for (int half = 0; half < 2; half++) {
    int b = lane + half * 64;
    float mu_ln = red[b * 2] * (1.f / FC);
    float var_ln = red[b * 2 + 1] * (1.f / FC) - mu_ln * mu_ln;
    float isg_ln = rsqrtf(var_ln + 1e-5f);

    union { ushort u[8]; uint4 v; } xu;
    xu.v = xeF[(size_t)f * BB + b];
    float xv[8];
#pragma unroll
    for (int k = 0; k < 8; k++) xv[k] = bf2f(xu.u[k]);
    float acc[8];
#pragma unroll
    for (int c = 0; c < 8; c++) acc[c] = bsm[fs][c];
#pragma unroll
    for (int k = 0; k < 8; k++) {
      const float4* wp = (const float4*)&wsm[fs][k * 8];
      float4 w0 = wp[0], w1 = wp[1];
      acc[0] += xv[k] * w0.x; acc[1] += xv[k] * w0.y;
      acc[2] += xv[k] * w0.z; acc[3] += xv[k] * w0.w;
      acc[4] += xv[k] * w1.x; acc[5] += xv[k] * w1.y;
      acc[6] += xv[k] * w1.z; acc[7] += xv[k] * w1.w;
    }
    float mu = 0.f;
#pragma unroll
    for (int c = 0; c < 8; c++) mu += acc[c];
    mu *= 0.125f;
    float var = 0.f;
#pragma unroll
    for (int c = 0; c < 8; c++) { float d = acc[c] - mu; var += d * d; }
    var *= 0.125f;
    float sc = rsqrtf(var + 1e-5f);

    union { ushort u[8]; uint4 v; } zu;
    zu.v = zT4[(size_t)f * BB + b];
    union { ushort u[8]; uint4 v; } pk;
#pragma unroll
    for (int c = 0; c < 8; c++) {
      float v = (acc[c] - mu) * sc;
      float sv = 1.f / (1.f + expf(-(bf2f(zu.u[c]) - mu_ln) * isg_ln));
      float hv = sv * v;
      hv = hv > 0.f ? hv : expm1f(hv);
      pk.u[c] = f2bf(hv);
    }
    hfcT4[(size_t)f * BB + b] = pk.v;
  }
}

// ---------------- layer part 2: xe = (fe? dot8(hfc[src], w3) : 0) + b3 + xe -------------
// fc blocks (0..3499): 2 f-octets, thread=(fs,b): 8 independent gather chains,
// residual read/modify/write = single uint4. out blocks (3500..3749): 4 edges, xeO.
__launch_bounds__(256)
__global__ void k_layer2(const uint4* __restrict__ hfcT4, const float* __restrict__ w3l,
                         const float* __restrict__ b3l, const int* __restrict__ map,
                         const int* __restrict__ src, uint4* __restrict__ xeF,
                         ushort* __restrict__ xeO) {
  __shared__ float wsm[16][8];
  __shared__ int gsm[16];
  __shared__ float bsm[16];
  int tid = threadIdx.x;
  if (blockIdx.x < 3500) {
    int e0 = blockIdx.x * 16;
    if (tid < 128) {
      int q = tid >> 3, c = tid & 7;
      int ii = map[e0 + q];
      wsm[q][c] = (ii >= 0) ? w3l[ii * 8 + c] : 0.f;
    } else if (tid < 144) {
      int q = tid - 128;
      gsm[q] = (map[e0 + q] >= 0) ? src[e0 + q] - NIN : -1;
    } else if (tid < 160) {
      int q = tid - 144;
      bsm[q] = b3l[e0 + q];
    }
    __syncthreads();
    int fs = tid >> 7, b = tid & 127;
    int f = blockIdx.x * 2 + fs;
    union { ushort u[8]; uint4 v; } xe8;
    xe8.v = xeF[(size_t)f * BB + b];
    union { ushort u[8]; uint4 v; } pk;
#pragma unroll
    for (int c = 0; c < 8; c++) {
      int q = fs * 8 + c;
      int g = gsm[q];
      float rv = bf2f(xe8.u[c]) + bsm[q];
      if (g >= 0) {
        union { ushort u[8]; uint4 v; } hv;
        hv.v = hfcT4[(size_t)g * BB + b];
        float a = 0.f;
#pragma unroll
        for (int j = 0; j < 8; j++) a += bf2f(hv.u[j]) * wsm[q][j];
        rv += a;
      }
      pk.u[c] = f2bf(rv);
    }
    xeF[(size_t)f * BB + b] = pk.v;
  } else {
    int e0 = FC + (blockIdx.x - 3500) * 4;
    if (tid < 32) {
      int q = tid;
      int ee = e0 + (q >> 3);
      int ii = map[ee];
      wsm[q >> 3][q & 7] = (ii >= 0) ? w3l[ii * 8 + (q & 7)] : 0.f;
    }
    __syncthreads();
    int es = tid >> 6, lane = tid & 63;
    int e = e0 + es;
    int i = map[e];
    int g = src[e] - NIN;
    float be = b3l[e];
#pragma unroll
    for (int half = 0; half < 2; half++) {
      int b = lane + half * 64;
      float rv = be + bf2f(xeO[(e - FC) * BB + b]);
      if (i >= 0) {
        union { ushort u[8]; uint4 v; } hv;
        hv.v = hfcT4[(size_t)g * BB + b];
        float a = 0.f;
#pragma unroll
        for (int c = 0; c < 8; c++) a += bf2f(hv.u[c]) * wsm[es][c];
        rv += a;
      }
      xeO[(e - FC) * BB + b] = f2bf(rv);
    }
  }
}

// ---------------- output: out[b, 11000+j] = xeO[j][b] / 4 ----------------
__global__ void k_out(const ushort* __restrict__ xeO, float* __restrict__ out) {
  __shared__ float t[32][33];
  int j0 = blockIdx.x * 32, b0 = blockIdx.y * 32;
  int tx = threadIdx.x, ty = threadIdx.y;
#pragma unroll
  for (int s2 = 0; s2 < 4; s2++) {
    int j = j0 + ty + s2 * 8;
    if (j < 1000) t[ty + s2 * 8][tx] = bf2f(xeO[j * BB + b0 + tx]);
  }
  __syncthreads();
#pragma unroll
  for (int s2 = 0; s2 < 4; s2++) {
    int b = b0 + ty + s2 * 8;
    int j = j0 + tx;
    if (j < 1000) out[b * NN + 11000 + j] = t[tx][ty + s2 * 8] * 0.25f;
  }
}

extern "C" void kernel_launch(void* const* d_in, const int* in_sizes, int n_in,
                              void* d_out, int out_size, void* d_ws, size_t ws_size,
                              hipStream_t stream) {
  const float* x = (const float*)d_in[0];
  const float* W_ae1 = (const float*)d_in[1];
  const float* b_ae1 = (const float*)d_in[2];
  const float* W_ae2 = (const float*)d_in[3];
  const float* b_ae2 = (const float*)d_in[4];
  const float* w1_vals = (const float*)d_in[5];
  const float* b1 = (const float*)d_in[6];
  const float* w3_vals = (const float*)d_in[7];
  const float* b3 = (const float*)d_in[8];
  const int* src = (const int*)d_in[9];
  const int* w3_cols = (const int*)d_in[14];

  int nnz3 = in_sizes[13];
  int n_fe = nnz3 / 8;

  // Workspace (f32 slot offsets); all uint4 regions 16B-aligned.
  float* W = (float*)d_ws;
  float* h_raw = W + 0;                   // 12,800  [k*128+b]
  float* red = W + 12800;                 // 256
  ushort* hbf = (ushort*)(W + 13056);     // 16,384 bf16 = 8,192 -> ends 21,248
  int* map = (int*)(W + 21248);           // 57,000 ints -> ends 78,248
  float* xT = W + 78400;                  // 1,536,000 -> ends 1,614,400
  uint4* xeF = (uint4*)(W + 1614400);     // 7000*128 uint4 = 3,584,000 -> ends 5,198,400
  ushort* xeO = (ushort*)(W + 5198400);   // 128,000 bf16 = 64,000 -> ends 5,262,400
  uint4* zT4 = (uint4*)(W + 5262400);     // 3,584,000 -> ends 8,846,400
  uint4* hfcT4 = (uint4*)(W + 8846400);   // 3,584,000 -> ends 12,430,400
  ushort* w2m = (ushort*)(W + 12430400);  // 3,584,000 -> ends 16,014,400

  hipMemsetAsync(h_raw, 0, 13056 * sizeof(float), stream);  // h_raw + red
  hipMemsetAsync(map, 0xFF, EE * sizeof(int), stream);
  hipMemsetAsync(d_out, 0, (size_t)out_size * sizeof(float), stream);

  k_transpose<<<dim3(NN / 32, BB / 32), dim3(32, 8), 0, stream>>>(x, xT);
  k_w2m<<<3500, 256, 0, stream>>>(W_ae2, w2m);
  k_ae1<<<dim3(25, 80), 128, 0, stream>>>(xT, W_ae1, h_raw);
  k_build_xe<<<4000, 256, 0, stream>>>(xT, src, xeF, xeO);
  k_map<<<(n_fe + 255) / 256, 256, 0, stream>>>(w3_cols, map, n_fe);
  k_hstage<<<8, 256, 0, stream>>>(h_raw, b_ae1, hbf);
  k_ae2<<<875, 256, 0, stream>>>(hbf, w2m, b_ae2, (ushort*)zT4, red);
  for (int l = 0; l < 4; l++) {
    k_layer1<<<NFN / 4, 256, 0, stream>>>(xeF, w1_vals + (size_t)l * 448000,
                                          b1 + (size_t)l * FC, zT4, red, hfcT4);
    k_layer2<<<3750, 256, 0, stream>>>(hfcT4, w3_vals + (size_t)l * nnz3,
                                       b3 + (size_t)l * EE, map, src, xeF, xeO);
  }
  k_out<<<dim3(32, 4), dim3(32, 8), 0, stream>>>(xeO, (float*)d_out);
}

// Round 12
// 294.233 us; speedup vs baseline: 1.1680x; 1.1042x over previous
//
#include <hip/hip_runtime.h>
#include <hip/hip_bf16.h>
#include <math.h>

#define BB 128
#define NN 12000
#define NIN 4000
#define NFN 7000
#define NOMIC 3600
#define FC 56000
#define EE 57000
#define LAT 100

typedef __hip_bfloat16 bf16;
typedef __attribute__((ext_vector_type(8))) short bf16x8;
typedef __attribute__((ext_vector_type(4))) float f32x4;

__device__ __forceinline__ ushort f2bf(float f) {
  bf16 h = __float2bfloat16(f);
  return *(ushort*)&h;
}
__device__ __forceinline__ float bf2f(ushort u) {
  bf16 h = *(bf16*)&u;
  return __bfloat162float(h);
}

// ---------------- transpose x (B,N) -> xT (N,B); also zero h_raw+red (13056 f32) -------
__global__ void k_transpose(const float* __restrict__ x, float* __restrict__ xT,
                            float* __restrict__ zr) {
  int flat = (blockIdx.y * 375 + blockIdx.x) * 256 + threadIdx.y * 32 + threadIdx.x;
  if (flat < 13056) zr[flat] = 0.f;
  __shared__ float t[32][33];
  int n0 = blockIdx.x * 32, b0 = blockIdx.y * 32;
  int tx = threadIdx.x, ty = threadIdx.y;
#pragma unroll
  for (int s = 0; s < 4; s++) {
    int b = b0 + ty + s * 8;
    int n = n0 + tx;
    t[ty + s * 8][tx] = x[b * NN + n];
  }
  __syncthreads();
#pragma unroll
  for (int s = 0; s < 4; s++) {
    int n = n0 + ty + s * 8;
    int b = b0 + tx;
    xT[n * BB + b] = t[tx][ty + s * 8];
  }
}

// ---------------- W2 -> bf16 A-frag layout; also map=-1 init and d_out zero ------------
// grid 6000x256 = 1,536,000 threads (= out_size).
__global__ void k_w2m(const float* __restrict__ W2, ushort* __restrict__ w2m,
                      int* __restrict__ map, float* __restrict__ out, int out_size) {
  int gid = blockIdx.x * 256 + threadIdx.x;
  if (gid < out_size) out[gid] = 0.f;
  if (gid < EE) map[gid] = -1;
  if (gid >= 3500 * 256) return;
  int lane = gid & 63;
  int JS = gid >> 6;
  int S = JS & 3, J = JS >> 2;
  int j = J * 16 + (lane & 15);
  int k0 = S * 32 + (lane >> 4) * 8;
  union { ushort u[8]; uint4 v; } p;
#pragma unroll
  for (int i = 0; i < 8; i++) {
    int k = k0 + i;
    p.u[i] = (k < LAT) ? f2bf(W2[(size_t)k * FC + j]) : (ushort)0;
  }
  *(uint4*)&w2m[(size_t)gid * 8] = p.v;
}

// ---------------- AE layer 1: h[k*128+b], split-K (80 chunks of 45) ----------------
__global__ void k_ae1(const float* __restrict__ xT, const float* __restrict__ W1,
                      float* __restrict__ h) {
  int b = threadIdx.x;
  int j0 = blockIdx.x * 4;
  int k0 = blockIdx.y * 45;
  float acc0 = 0.f, acc1 = 0.f, acc2 = 0.f, acc3 = 0.f;
  const float* xp = &xT[(size_t)k0 * BB + b];
  const float* wp = &W1[(size_t)k0 * LAT + j0];
#pragma unroll 5
  for (int kk = 0; kk < 45; kk++) {
    float xv = xp[kk * BB];
    float4 w = *(const float4*)(wp + kk * LAT);
    acc0 += xv * w.x; acc1 += xv * w.y; acc2 += xv * w.z; acc3 += xv * w.w;
  }
  atomicAdd(&h[(j0 + 0) * BB + b], acc0);
  atomicAdd(&h[(j0 + 1) * BB + b], acc1);
  atomicAdd(&h[(j0 + 2) * BB + b], acc2);
  atomicAdd(&h[(j0 + 3) * BB + b], acc3);
}

// ---------------- elu(h+b_ae1) -> hbf in MFMA B-frag-ready layout ---------------------
__global__ void k_hstage(const float* __restrict__ h, const float* __restrict__ b_ae1,
                         ushort* __restrict__ hbf) {
  int gid = blockIdx.x * 256 + threadIdx.x;  // 2048 groups of 8
  int lane = gid & 63;
  int St = gid >> 6;  // 0..31
  int S = St >> 3, t = St & 7;
  int b = t * 16 + (lane & 15);
  int k0 = S * 32 + (lane >> 4) * 8;
  union { ushort u[8]; uint4 v; } p;
#pragma unroll
  for (int i = 0; i < 8; i++) {
    int k = k0 + i;
    if (k < LAT) {
      float v = h[k * BB + b] + b_ae1[k];
      p.u[i] = f2bf(v > 0.f ? v : expm1f(v));
    } else {
      p.u[i] = 0;
    }
  }
  *(uint4*)&hbf[(size_t)gid * 8] = p.v;
}

// ---------------- build edge state xeF/xeO; also fill map from w3_cols -----------------
__global__ void k_build_xe(const float* __restrict__ xT, const int* __restrict__ src,
                           uint4* __restrict__ xeF, ushort* __restrict__ xeO,
                           const int* __restrict__ w3_cols, int* __restrict__ map,
                           int n_fe) {
  int gid = blockIdx.x * 256 + threadIdx.x;
  if (gid < NFN * BB) {
    int f = gid >> 7, b = gid & 127;
    union { ushort u[8]; uint4 v; } p;
#pragma unroll
    for (int c = 0; c < 8; c++) {
      int s = src[f * 8 + c];
      p.u[c] = (s < NOMIC) ? (ushort)f2bf(0.f) : f2bf(xT[s * BB + b]);
    }
    xeF[(size_t)f * BB + b] = p.v;
  } else if (gid < NFN * BB + 1000 * BB) {
    int idx = gid - NFN * BB;
    int eo = idx >> 7, b = idx & 127;
    int s = src[FC + eo];
    xeO[idx] = (s < NOMIC) ? (ushort)f2bf(0.f) : f2bf(xT[s * BB + b]);
  } else {
    int i = gid - (NFN * BB + 1000 * BB);
    if (i < n_fe) map[w3_cols[i * 8]] = i;
  }
}

// ---------------- AE layer 2 GEMM via MFMA: zT[f][b][c](bf16) = h @ W2 + b2, + LN sums --
__launch_bounds__(256)
__global__ void k_ae2(const ushort* __restrict__ hbf, const ushort* __restrict__ w2m,
                      const float* __restrict__ b_ae2, ushort* __restrict__ zT,
                      float* __restrict__ red) {
  __shared__ __align__(16) ushort hB[16384];  // 32 KB B-frag-ready h
  __shared__ float lred[256];
  int tid = threadIdx.x;
  lred[tid] = 0.f;
  for (int i = tid * 8; i < 16384; i += 256 * 8)
    *(uint4*)&hB[i] = *(const uint4*)&hbf[i];
  __syncthreads();

  int wave = tid >> 6, lane = tid & 63;
  int J = blockIdx.x * 4 + wave;  // j-tile (3500 total)
  int j0 = J * 16;
  int q = lane >> 4, n = lane & 15;

  bf16x8 a[4];
#pragma unroll
  for (int S = 0; S < 4; S++)
    a[S] = *(const bf16x8*)&w2m[(size_t)((J * 4 + S) * 64 + lane) * 8];

  float4 bias = *(const float4*)&b_ae2[j0 + q * 4];
  int jb = j0 + q * 4;
  int f = jb >> 3, c0 = jb & 7;

#pragma unroll
  for (int t = 0; t < 8; t++) {
    f32x4 acc = (f32x4){0.f, 0.f, 0.f, 0.f};
#pragma unroll
    for (int S = 0; S < 4; S++) {
      bf16x8 bfr = *(const bf16x8*)&hB[((S * 8 + t) * 64 + lane) * 8];
      acc = __builtin_amdgcn_mfma_f32_16x16x32_bf16(a[S], bfr, acc, 0, 0, 0);
    }
    int b = t * 16 + n;
    float v0 = acc[0] + bias.x, v1 = acc[1] + bias.y;
    float v2 = acc[2] + bias.z, v3 = acc[3] + bias.w;
    ushort4 pk;
    pk.x = f2bf(v0); pk.y = f2bf(v1); pk.z = f2bf(v2); pk.w = f2bf(v3);
    *(ushort4*)&zT[(size_t)f * 1024 + b * 8 + c0] = pk;
    float s = v0 + v1 + v2 + v3;
    float qq = v0 * v0 + v1 * v1 + v2 * v2 + v3 * v3;
    atomicAdd(&lred[b * 2], s);
    atomicAdd(&lred[b * 2 + 1], qq);
  }
  __syncthreads();
  atomicAdd(&red[tid], lred[tid]);
}

// ---------------- first layer1: hfc = elu(s * groupLN(8x8 matmul(xe) + b1)) ------------
__launch_bounds__(256)
__global__ void k_layer1(const uint4* __restrict__ xeF, const float* __restrict__ w1l,
                         const float* __restrict__ b1l, const uint4* __restrict__ zT4,
                         const float* __restrict__ red, uint4* __restrict__ hfcT4) {
  __shared__ __align__(16) float wsm[4][64];
  __shared__ float bsm[4][8];
  int tid = threadIdx.x;
  int fs = tid >> 6;   // 0..3
  int lane = tid & 63;
  int f = blockIdx.x * 4 + fs;
  wsm[tid >> 6][tid & 63] = w1l[blockIdx.x * 256 + tid];
  if (tid < 32) bsm[tid >> 3][tid & 7] = b1l[blockIdx.x * 32 + tid];
  __syncthreads();

#pragma unroll
  for (int half = 0; half < 2; half++) {
    int b = lane + half * 64;
    float mu_ln = red[b * 2] * (1.f / FC);
    float var_ln = red[b * 2 + 1] * (1.f / FC) - mu_ln * mu_ln;
    float isg_ln = rsqrtf(var_ln + 1e-5f);

    union { ushort u[8]; uint4 v; } xu;
    xu.v = xeF[(size_t)f * BB + b];
    float xv[8];
#pragma unroll
    for (int k = 0; k < 8; k++) xv[k] = bf2f(xu.u[k]);
    float acc[8];
#pragma unroll
    for (int c = 0; c < 8; c++) acc[c] = bsm[fs][c];
#pragma unroll
    for (int k = 0; k < 8; k++) {
      const float4* wp = (const float4*)&wsm[fs][k * 8];
      float4 w0 = wp[0], w1 = wp[1];
      acc[0] += xv[k] * w0.x; acc[1] += xv[k] * w0.y;
      acc[2] += xv[k] * w0.z; acc[3] += xv[k] * w0.w;
      acc[4] += xv[k] * w1.x; acc[5] += xv[k] * w1.y;
      acc[6] += xv[k] * w1.z; acc[7] += xv[k] * w1.w;
    }
    float mu = 0.f;
#pragma unroll
    for (int c = 0; c < 8; c++) mu += acc[c];
    mu *= 0.125f;
    float var = 0.f;
#pragma unroll
    for (int c = 0; c < 8; c++) { float d = acc[c] - mu; var += d * d; }
    var *= 0.125f;
    float sc = rsqrtf(var + 1e-5f);

    union { ushort u[8]; uint4 v; } zu;
    zu.v = zT4[(size_t)f * BB + b];
    union { ushort u[8]; uint4 v; } pk;
#pragma unroll
    for (int c = 0; c < 8; c++) {
      float v = (acc[c] - mu) * sc;
      float sv = 1.f / (1.f + expf(-(bf2f(zu.u[c]) - mu_ln) * isg_ln));
      float hv = sv * v;
      hv = hv > 0.f ? hv : expm1f(hv);
      pk.u[c] = f2bf(hv);
    }
    hfcT4[(size_t)f * BB + b] = pk.v;
  }
}

// ---------------- fused: layer2(l) [+ layer1(l+1) if do_l1] ---------------------------
// fc blocks (0..3499): 2 f-octets; thread (fs,b). New xe stays in regs for layer1.
// out blocks (3500..3749): 4 out-edges, xeO update only.
__launch_bounds__(256)
__global__ void k_fused(const uint4* __restrict__ hfcIn, const float* __restrict__ w3l,
                        const float* __restrict__ b3l, const int* __restrict__ map,
                        const int* __restrict__ src, uint4* __restrict__ xeF,
                        ushort* __restrict__ xeO, const float* __restrict__ w1n,
                        const float* __restrict__ b1n, const uint4* __restrict__ zT4,
                        const float* __restrict__ red, uint4* __restrict__ hfcOut,
                        int do_l1) {
  __shared__ float wsm3[16][8];
  __shared__ int gsm[16];
  __shared__ float bsm3[16];
  __shared__ __align__(16) float w1sm[2][64];
  __shared__ float b1sm[2][8];
  int tid = threadIdx.x;
  if (blockIdx.x < 3500) {
    int e0 = blockIdx.x * 16;
    if (tid < 128) {
      int q = tid >> 3, c = tid & 7;
      int ii = map[e0 + q];
      wsm3[q][c] = (ii >= 0) ? w3l[ii * 8 + c] : 0.f;
      if (do_l1) w1sm[tid >> 6][tid & 63] = w1n[blockIdx.x * 128 + tid];
    } else if (tid < 144) {
      int q = tid - 128;
      gsm[q] = (map[e0 + q] >= 0) ? src[e0 + q] - NIN : -1;
    } else if (tid < 160) {
      int q = tid - 144;
      bsm3[q] = b3l[e0 + q];
    } else if (tid < 176) {
      if (do_l1) {
        int q = tid - 160;
        b1sm[q >> 3][q & 7] = b1n[blockIdx.x * 16 + q];
      }
    }
    __syncthreads();
    int fs = tid >> 7, b = tid & 127;
    int f = blockIdx.x * 2 + fs;
    union { ushort u[8]; uint4 v; } xe8;
    xe8.v = xeF[(size_t)f * BB + b];
    union { ushort u[8]; uint4 v; } pk;
#pragma unroll
    for (int c = 0; c < 8; c++) {
      int q = fs * 8 + c;
      int g = gsm[q];
      float rv = bf2f(xe8.u[c]) + bsm3[q];
      if (g >= 0) {
        union { ushort u[8]; uint4 v; } hv;
        hv.v = hfcIn[(size_t)g * BB + b];
        float a = 0.f;
#pragma unroll
        for (int j = 0; j < 8; j++) a += bf2f(hv.u[j]) * wsm3[q][j];
        rv += a;
      }
      pk.u[c] = f2bf(rv);
    }
    xeF[(size_t)f * BB + b] = pk.v;

    if (do_l1) {
      // layer1(l+1) on bf16-rounded xe (parity with unfused read-back)
      float xv[8];
#pragma unroll
      for (int k = 0; k < 8; k++) xv[k] = bf2f(pk.u[k]);
      float mu_ln = red[b * 2] * (1.f / FC);
      float var_ln = red[b * 2 + 1] * (1.f / FC) - mu_ln * mu_ln;
      float isg_ln = rsqrtf(var_ln + 1e-5f);
      float acc[8];
#pragma unroll
      for (int c = 0; c < 8; c++) acc[c] = b1sm[fs][c];
#pragma unroll
      for (int k = 0; k < 8; k++) {
        const float4* wp = (const float4*)&w1sm[fs][k * 8];
        float4 w0 = wp[0], w1 = wp[1];
        acc[0] += xv[k] * w0.x; acc[1] += xv[k] * w0.y;
        acc[2] += xv[k] * w0.z; acc[3] += xv[k] * w0.w;
        acc[4] += xv[k] * w1.x; acc[5] += xv[k] * w1.y;
        acc[6] += xv[k] * w1.z; acc[7] += xv[k] * w1.w;
      }
      float mu = 0.f;
#pragma unroll
      for (int c = 0; c < 8; c++) mu += acc[c];
      mu *= 0.125f;
      float var = 0.f;
#pragma unroll
      for (int c = 0; c < 8; c++) { float d = acc[c] - mu; var += d * d; }
      var *= 0.125f;
      float sc = rsqrtf(var + 1e-5f);
      union { ushort u[8]; uint4 v; } zu;
      zu.v = zT4[(size_t)f * BB + b];
      union { ushort u[8]; uint4 v; } hk;
#pragma unroll
      for (int c = 0; c < 8; c++) {
        float v = (acc[c] - mu) * sc;
        float sv = 1.f / (1.f + expf(-(bf2f(zu.u[c]) - mu_ln) * isg_ln));
        float hv = sv * v;
        hv = hv > 0.f ? hv : expm1f(hv);
        hk.u[c] = f2bf(hv);
      }
      hfcOut[(size_t)f * BB + b] = hk.v;
    }
  } else {
    int e0 = FC + (blockIdx.x - 3500) * 4;
    if (tid < 32) {
      int q = tid;
      int ee = e0 + (q >> 3);
      int ii = map[ee];
      wsm3[q >> 3][q & 7] = (ii >= 0) ? w3l[ii * 8 + (q & 7)] : 0.f;
    }
    __syncthreads();
    int es = tid >> 6, lane = tid & 63;
    int e = e0 + es;
    int i = map[e];
    int g = src[e] - NIN;
    float be = b3l[e];
#pragma unroll
    for (int half = 0; half < 2; half++) {
      int b = lane + half * 64;
      float rv = be + bf2f(xeO[(e - FC) * BB + b]);
      if (i >= 0) {
        union { ushort u[8]; uint4 v; } hv;
        hv.v = hfcIn[(size_t)g * BB + b];
        float a = 0.f;
#pragma unroll
        for (int c = 0; c < 8; c++) a += bf2f(hv.u[c]) * wsm3[es][c];
        rv += a;
      }
      xeO[(e - FC) * BB + b] = f2bf(rv);
    }
  }
}

// ---------------- output: out[b, 11000+j] = xeO[j][b] / 4 ----------------
__global__ void k_out(const ushort* __restrict__ xeO, float* __restrict__ out) {
  __shared__ float t[32][33];
  int j0 = blockIdx.x * 32, b0 = blockIdx.y * 32;
  int tx = threadIdx.x, ty = threadIdx.y;
#pragma unroll
  for (int s2 = 0; s2 < 4; s2++) {
    int j = j0 + ty + s2 * 8;
    if (j < 1000) t[ty + s2 * 8][tx] = bf2f(xeO[j * BB + b0 + tx]);
  }
  __syncthreads();
#pragma unroll
  for (int s2 = 0; s2 < 4; s2++) {
    int b = b0 + ty + s2 * 8;
    int j = j0 + tx;
    if (j < 1000) out[b * NN + 11000 + j] = t[tx][ty + s2 * 8] * 0.25f;
  }
}

extern "C" void kernel_launch(void* const* d_in, const int* in_sizes, int n_in,
                              void* d_out, int out_size, void* d_ws, size_t ws_size,
                              hipStream_t stream) {
  const float* x = (const float*)d_in[0];
  const float* W_ae1 = (const float*)d_in[1];
  const float* b_ae1 = (const float*)d_in[2];
  const float* W_ae2 = (const float*)d_in[3];
  const float* b_ae2 = (const float*)d_in[4];
  const float* w1_vals = (const float*)d_in[5];
  const float* b1 = (const float*)d_in[6];
  const float* w3_vals = (const float*)d_in[7];
  const float* b3 = (const float*)d_in[8];
  const int* src = (const int*)d_in[9];
  const int* w3_cols = (const int*)d_in[14];

  int nnz3 = in_sizes[13];
  int n_fe = nnz3 / 8;

  // Workspace (f32 slot offsets); all uint4 regions 16B-aligned.
  float* W = (float*)d_ws;
  float* h_raw = W + 0;                   // 12,800  [k*128+b]
  float* red = W + 12800;                 // 256  (h_raw+red zeroed by k_transpose)
  ushort* hbf = (ushort*)(W + 13056);     // 8,192 -> ends 21,248
  int* map = (int*)(W + 21248);           // 57,000 ints -> ends 78,248
  float* xT = W + 78400;                  // 1,536,000 -> ends 1,614,400
  uint4* xeF = (uint4*)(W + 1614400);     // 3,584,000 -> ends 5,198,400
  ushort* xeO = (ushort*)(W + 5198400);   // 64,000 -> ends 5,262,400
  uint4* zT4 = (uint4*)(W + 5262400);     // 3,584,000 -> ends 8,846,400
  uint4* hfcA = (uint4*)(W + 8846400);    // 3,584,000 -> ends 12,430,400
  uint4* hfcB = (uint4*)(W + 12430400);   // 3,584,000 -> ends 16,014,400
  ushort* w2m = (ushort*)(W + 16014400);  // 3,584,000 -> ends 19,598,400

  k_transpose<<<dim3(NN / 32, BB / 32), dim3(32, 8), 0, stream>>>(x, xT, h_raw);
  k_w2m<<<6000, 256, 0, stream>>>(W_ae2, w2m, map, (float*)d_out, out_size);
  k_ae1<<<dim3(25, 80), 128, 0, stream>>>(xT, W_ae1, h_raw);
  k_build_xe<<<4000 + (n_fe + 255) / 256, 256, 0, stream>>>(xT, src, xeF, xeO,
                                                            w3_cols, map, n_fe);
  k_hstage<<<8, 256, 0, stream>>>(h_raw, b_ae1, hbf);
  k_ae2<<<875, 256, 0, stream>>>(hbf, w2m, b_ae2, (ushort*)zT4, red);

  // layer1(0)
  k_layer1<<<NFN / 4, 256, 0, stream>>>(xeF, w1_vals, b1, zT4, red, hfcA);
  // fused layer2(l) + layer1(l+1), hfc ping-pong
  uint4* hin = hfcA;
  uint4* hout = hfcB;
  for (int l = 0; l < 4; l++) {
    int do_l1 = (l < 3) ? 1 : 0;
    k_fused<<<3750, 256, 0, stream>>>(hin, w3_vals + (size_t)l * nnz3,
                                      b3 + (size_t)l * EE, map, src, xeF, xeO,
                                      w1_vals + (size_t)(l + 1) * 448000 * (size_t)do_l1,
                                      b1 + (size_t)(l + 1) * FC * (size_t)do_l1,
                                      zT4, red, hout, do_l1);
    uint4* tmp = hin; hin = hout; hout = tmp;
  }
  k_out<<<dim3(32, 4), dim3(32, 8), 0, stream>>>(xeO, (float*)d_out);
}

// Round 15
// 287.256 us; speedup vs baseline: 1.1963x; 1.0243x over previous
//
#include <hip/hip_runtime.h>
#include <hip/hip_bf16.h>
#include <math.h>

#define BB 128
#define NN 12000
#define NIN 4000
#define NFN 7000
#define NOMIC 3600
#define FC 56000
#define EE 57000
#define LAT 100

typedef __hip_bfloat16 bf16;
typedef __attribute__((ext_vector_type(8))) short bf16x8;
typedef __attribute__((ext_vector_type(4))) float f32x4;

__device__ __forceinline__ ushort f2bf(float f) {
  bf16 h = __float2bfloat16(f);
  return *(ushort*)&h;
}
__device__ __forceinline__ float bf2f(ushort u) {
  bf16 h = *(bf16*)&u;
  return __bfloat162float(h);
}

// ---- prep0: transpose + w2m frag + zero(d_out, map, h_raw/red). All independent. ----
// grid = 6774 x 256: [0,1500) transpose, [1500,5000) w2m, [5000,6500) zero out,
// [6500,6723) map=-1, [6723,6774) zero h_raw+red.
__global__ void k_prep0(const float* __restrict__ x, float* __restrict__ xT,
                        const float* __restrict__ W2, ushort* __restrict__ w2m,
                        int* __restrict__ map, float* __restrict__ out,
                        float* __restrict__ hzero) {
  int u = blockIdx.x;
  int tid = threadIdx.x;
  if (u < 1500) {
    __shared__ float t[32][33];
    int n0 = (u % 375) * 32, b0 = (u / 375) * 32;
    int tx = tid & 31, ty = tid >> 5;
#pragma unroll
    for (int s = 0; s < 4; s++)
      t[ty + s * 8][tx] = x[(b0 + ty + s * 8) * NN + n0 + tx];
    __syncthreads();
#pragma unroll
    for (int s = 0; s < 4; s++)
      xT[(n0 + ty + s * 8) * BB + b0 + tx] = t[tx][ty + s * 8];
  } else if (u < 5000) {
    int gid = (u - 1500) * 256 + tid;
    int lane = gid & 63;
    int JS = gid >> 6;
    int S = JS & 3, J = JS >> 2;
    int j = J * 16 + (lane & 15);
    int k0 = S * 32 + (lane >> 4) * 8;
    union { ushort uu[8]; uint4 v; } p;
#pragma unroll
    for (int i = 0; i < 8; i++) {
      int k = k0 + i;
      p.uu[i] = (k < LAT) ? f2bf(W2[(size_t)k * FC + j]) : (ushort)0;
    }
    *(uint4*)&w2m[(size_t)gid * 8] = p.v;
  } else if (u < 6500) {
    int idx = (u - 5000) * 256 + tid;  // 384,000 float4 = out_size/4 exactly
    ((float4*)out)[idx] = make_float4(0.f, 0.f, 0.f, 0.f);
  } else if (u < 6723) {
    int i = (u - 6500) * 256 + tid;
    if (i < EE) map[i] = -1;
  } else {
    int i = (u - 6723) * 256 + tid;
    if (i < 13056) hzero[i] = 0.f;  // h_raw (12800) + red (256), contiguous
  }
}

// ---- AE layer 1: h[k*128+b], split-K (80 chunks of 45), atomics ----
__global__ void k_ae1(const float* __restrict__ xT, const float* __restrict__ W1,
                      float* __restrict__ h) {
  int b = threadIdx.x;
  int j0 = blockIdx.x * 4;
  int k0 = blockIdx.y * 45;
  float acc0 = 0.f, acc1 = 0.f, acc2 = 0.f, acc3 = 0.f;
  const float* xp = &xT[(size_t)k0 * BB + b];
  const float* wp = &W1[(size_t)k0 * LAT + j0];
#pragma unroll 5
  for (int kk = 0; kk < 45; kk++) {
    float xv = xp[kk * BB];
    float4 w = *(const float4*)(wp + kk * LAT);
    acc0 += xv * w.x; acc1 += xv * w.y; acc2 += xv * w.z; acc3 += xv * w.w;
  }
  atomicAdd(&h[(j0 + 0) * BB + b], acc0);
  atomicAdd(&h[(j0 + 1) * BB + b], acc1);
  atomicAdd(&h[(j0 + 2) * BB + b], acc2);
  atomicAdd(&h[(j0 + 3) * BB + b], acc3);
}

// ---- prep1 (after ae1): build_xe + xeO + hstage + map-fill. All independent. ----
// grid = 4008 + ceil(n_fe/256): [0,3500) xeF, [3500,4000) xeO, [4000,4008) hstage,
// [4008,...) map fill.
__global__ void k_prep1(const float* __restrict__ xT, const int* __restrict__ src,
                        uint4* __restrict__ xeF, ushort* __restrict__ xeO,
                        const float* __restrict__ h, const float* __restrict__ b_ae1,
                        ushort* __restrict__ hbf, const int* __restrict__ w3_cols,
                        int* __restrict__ map, int n_fe) {
  int u = blockIdx.x;
  int tid = threadIdx.x;
  if (u < 3500) {
    int gid = u * 256 + tid;
    int f = gid >> 7, b = gid & 127;
    union { ushort uu[8]; uint4 v; } p;
#pragma unroll
    for (int c = 0; c < 8; c++) {
      int s = src[f * 8 + c];
      p.uu[c] = (s < NOMIC) ? (ushort)f2bf(0.f) : f2bf(xT[s * BB + b]);
    }
    xeF[(size_t)f * BB + b] = p.v;
  } else if (u < 4000) {
    int idx = (u - 3500) * 256 + tid;
    int eo = idx >> 7, b = idx & 127;
    int s = src[FC + eo];
    xeO[idx] = (s < NOMIC) ? (ushort)f2bf(0.f) : f2bf(xT[s * BB + b]);
  } else if (u < 4008) {
    int gid = (u - 4000) * 256 + tid;
    int lane = gid & 63;
    int St = gid >> 6;
    int S = St >> 3, t = St & 7;
    int b = t * 16 + (lane & 15);
    int k0 = S * 32 + (lane >> 4) * 8;
    union { ushort uu[8]; uint4 v; } p;
#pragma unroll
    for (int i = 0; i < 8; i++) {
      int k = k0 + i;
      if (k < LAT) {
        float v = h[k * BB + b] + b_ae1[k];
        p.uu[i] = f2bf(v > 0.f ? v : expm1f(v));
      } else {
        p.uu[i] = 0;
      }
    }
    *(uint4*)&hbf[(size_t)gid * 8] = p.v;
  } else {
    int i = (u - 4008) * 256 + tid;
    if (i < n_fe) map[w3_cols[i * 8]] = i;
  }
}

// ---- AE layer 2 GEMM via MFMA: zT[f][b][c](bf16) = h @ W2 + b2, + LN sums ----
__launch_bounds__(256)
__global__ void k_ae2(const ushort* __restrict__ hbf, const ushort* __restrict__ w2m,
                      const float* __restrict__ b_ae2, ushort* __restrict__ zT,
                      float* __restrict__ red) {
  __shared__ __align__(16) ushort hB[16384];
  __shared__ float lred[256];
  int tid = threadIdx.x;
  lred[tid] = 0.f;
  for (int i = tid * 8; i < 16384; i += 256 * 8)
    *(uint4*)&hB[i] = *(const uint4*)&hbf[i];
  __syncthreads();
  int wave = tid >> 6, lane = tid & 63;
  int J = blockIdx.x * 4 + wave;
  int j0 = J * 16;
  int q = lane >> 4, n = lane & 15;
  bf16x8 a[4];
#pragma unroll
  for (int S = 0; S < 4; S++)
    a[S] = *(const bf16x8*)&w2m[(size_t)((J * 4 + S) * 64 + lane) * 8];
  float4 bias = *(const float4*)&b_ae2[j0 + q * 4];
  int jb = j0 + q * 4;
  int f = jb >> 3, c0 = jb & 7;
#pragma unroll
  for (int t = 0; t < 8; t++) {
    f32x4 acc = (f32x4){0.f, 0.f, 0.f, 0.f};
#pragma unroll
    for (int S = 0; S < 4; S++) {
      bf16x8 bfr = *(const bf16x8*)&hB[((S * 8 + t) * 64 + lane) * 8];
      acc = __builtin_amdgcn_mfma_f32_16x16x32_bf16(a[S], bfr, acc, 0, 0, 0);
    }
    int b = t * 16 + n;
    float v0 = acc[0] + bias.x, v1 = acc[1] + bias.y;
    float v2 = acc[2] + bias.z, v3 = acc[3] + bias.w;
    ushort4 pk;
    pk.x = f2bf(v0); pk.y = f2bf(v1); pk.z = f2bf(v2); pk.w = f2bf(v3);
    *(ushort4*)&zT[(size_t)f * 1024 + b * 8 + c0] = pk;
    atomicAdd(&lred[b * 2], v0 + v1 + v2 + v3);
    atomicAdd(&lred[b * 2 + 1], v0 * v0 + v1 * v1 + v2 * v2 + v3 * v3);
  }
  __syncthreads();
  atomicAdd(&red[tid], lred[tid]);
}

// ---- layer1(0): hfc = elu(s * groupLN(8x8 matmul(xe) + b1)) ----
__launch_bounds__(256)
__global__ void k_layer1(const uint4* __restrict__ xeF, const float* __restrict__ w1l,
                         const float* __restrict__ b1l, const uint4* __restrict__ zT4,
                         const float* __restrict__ red, uint4* __restrict__ hfcT4) {
  __shared__ __align__(16) float wsm[4][64];
  __shared__ float bsm[4][8];
  int tid = threadIdx.x;
  int fs = tid >> 6;
  int lane = tid & 63;
  int f = blockIdx.x * 4 + fs;
  wsm[tid >> 6][tid & 63] = w1l[blockIdx.x * 256 + tid];
  if (tid < 32) bsm[tid >> 3][tid & 7] = b1l[blockIdx.x * 32 + tid];
  __syncthreads();
#pragma unroll
  for (int half = 0; half < 2; half++) {
    int b = lane + half * 64;
    float mu_ln = red[b * 2] * (1.f / FC);
    float var_ln = red[b * 2 + 1] * (1.f / FC) - mu_ln * mu_ln;
    float isg_ln = rsqrtf(var_ln + 1e-5f);
    union { ushort u[8]; uint4 v; } xu;
    xu.v = xeF[(size_t)f * BB + b];
    float xv[8];
#pragma unroll
    for (int k = 0; k < 8; k++) xv[k] = bf2f(xu.u[k]);
    float acc[8];
#pragma unroll
    for (int c = 0; c < 8; c++) acc[c] = bsm[fs][c];
#pragma unroll
    for (int k = 0; k < 8; k++) {
      const float4* wp = (const float4*)&wsm[fs][k * 8];
      float4 w0 = wp[0], w1 = wp[1];
      acc[0] += xv[k] * w0.x; acc[1] += xv[k] * w0.y;
      acc[2] += xv[k] * w0.z; acc[3] += xv[k] * w0.w;
      acc[4] += xv[k] * w1.x; acc[5] += xv[k] * w1.y;
      acc[6] += xv[k] * w1.z; acc[7] += xv[k] * w1.w;
    }
    float mu = 0.f;
#pragma unroll
    for (int c = 0; c < 8; c++) mu += acc[c];
    mu *= 0.125f;
    float var = 0.f;
#pragma unroll
    for (int c = 0; c < 8; c++) { float d = acc[c] - mu; var += d * d; }
    var *= 0.125f;
    float sc = rsqrtf(var + 1e-5f);
    union { ushort u[8]; uint4 v; } zu;
    zu.v = zT4[(size_t)f * BB + b];
    union { ushort u[8]; uint4 v; } pk;
#pragma unroll
    for (int c = 0; c < 8; c++) {
      float v = (acc[c] - mu) * sc;
      float sv = 1.f / (1.f + expf(-(bf2f(zu.u[c]) - mu_ln) * isg_ln));
      float hv = sv * v;
      hv = hv > 0.f ? hv : expm1f(hv);
      pk.u[c] = f2bf(hv);
    }
    hfcT4[(size_t)f * BB + b] = pk.v;
  }
}

// ---- fused layer2(l) + layer1(l+1) ----
__launch_bounds__(256)
__global__ void k_fused(const uint4* __restrict__ hfcIn, const float* __restrict__ w3l,
                        const float* __restrict__ b3l, const int* __restrict__ map,
                        const int* __restrict__ src, uint4* __restrict__ xeF,
                        ushort* __restrict__ xeO, const float* __restrict__ w1n,
                        const float* __restrict__ b1n, const uint4* __restrict__ zT4,
                        const float* __restrict__ red, uint4* __restrict__ hfcOut,
                        int do_l1) {
  __shared__ float wsm3[16][8];
  __shared__ int gsm[16];
  __shared__ float bsm3[16];
  __shared__ __align__(16) float w1sm[2][64];
  __shared__ float b1sm[2][8];
  int tid = threadIdx.x;
  if (blockIdx.x < 3500) {
    int e0 = blockIdx.x * 16;
    if (tid < 128) {
      int q = tid >> 3, c = tid & 7;
      int ii = map[e0 + q];
      wsm3[q][c] = (ii >= 0) ? w3l[ii * 8 + c] : 0.f;
      if (do_l1) w1sm[tid >> 6][tid & 63] = w1n[blockIdx.x * 128 + tid];
    } else if (tid < 144) {
      int q = tid - 128;
      gsm[q] = (map[e0 + q] >= 0) ? src[e0 + q] - NIN : -1;
    } else if (tid < 160) {
      int q = tid - 144;
      bsm3[q] = b3l[e0 + q];
    } else if (tid < 176 && do_l1) {
      int q = tid - 160;
      b1sm[q >> 3][q & 7] = b1n[blockIdx.x * 16 + q];
    }
    __syncthreads();
    int fs = tid >> 7, b = tid & 127;
    int f = blockIdx.x * 2 + fs;
    union { ushort u[8]; uint4 v; } xe8;
    xe8.v = xeF[(size_t)f * BB + b];
    union { ushort u[8]; uint4 v; } pk;
#pragma unroll
    for (int c = 0; c < 8; c++) {
      int q = fs * 8 + c;
      int g = gsm[q];
      float rv = bf2f(xe8.u[c]) + bsm3[q];
      if (g >= 0) {
        union { ushort u[8]; uint4 v; } hv;
        hv.v = hfcIn[(size_t)g * BB + b];
        float a = 0.f;
#pragma unroll
        for (int j = 0; j < 8; j++) a += bf2f(hv.u[j]) * wsm3[q][j];
        rv += a;
      }
      pk.u[c] = f2bf(rv);
    }
    xeF[(size_t)f * BB + b] = pk.v;
    if (do_l1) {
      float xv[8];
#pragma unroll
      for (int k = 0; k < 8; k++) xv[k] = bf2f(pk.u[k]);
      float mu_ln = red[b * 2] * (1.f / FC);
      float var_ln = red[b * 2 + 1] * (1.f / FC) - mu_ln * mu_ln;
      float isg_ln = rsqrtf(var_ln + 1e-5f);
      float acc[8];
#pragma unroll
      for (int c = 0; c < 8; c++) acc[c] = b1sm[fs][c];
#pragma unroll
      for (int k = 0; k < 8; k++) {
        const float4* wp = (const float4*)&w1sm[fs][k * 8];
        float4 w0 = wp[0], w1 = wp[1];
        acc[0] += xv[k] * w0.x; acc[1] += xv[k] * w0.y;
        acc[2] += xv[k] * w0.z; acc[3] += xv[k] * w0.w;
        acc[4] += xv[k] * w1.x; acc[5] += xv[k] * w1.y;
        acc[6] += xv[k] * w1.z; acc[7] += xv[k] * w1.w;
      }
      float mu = 0.f;
#pragma unroll
      for (int c = 0; c < 8; c++) mu += acc[c];
      mu *= 0.125f;
      float var = 0.f;
#pragma unroll
      for (int c = 0; c < 8; c++) { float d = acc[c] - mu; var += d * d; }
      var *= 0.125f;
      float sc = rsqrtf(var + 1e-5f);
      union { ushort u[8]; uint4 v; } zu;
      zu.v = zT4[(size_t)f * BB + b];
      union { ushort u[8]; uint4 v; } hk;
#pragma unroll
      for (int c = 0; c < 8; c++) {
        float v = (acc[c] - mu) * sc;
        float sv = 1.f / (1.f + expf(-(bf2f(zu.u[c]) - mu_ln) * isg_ln));
        float hv = sv * v;
        hv = hv > 0.f ? hv : expm1f(hv);
        hk.u[c] = f2bf(hv);
      }
      hfcOut[(size_t)f * BB + b] = hk.v;
    }
  } else {
    int e0 = FC + (blockIdx.x - 3500) * 4;
    if (tid < 32) {
      int q = tid;
      int ee = e0 + (q >> 3);
      int ii = map[ee];
      wsm3[q >> 3][q & 7] = (ii >= 0) ? w3l[ii * 8 + (q & 7)] : 0.f;
    }
    __syncthreads();
    int es = tid >> 6, lane = tid & 63;
    int e = e0 + es;
    int i = map[e];
    int g = src[e] - NIN;
    float be = b3l[e];
#pragma unroll
    for (int half = 0; half < 2; half++) {
      int b = lane + half * 64;
      float rv = be + bf2f(xeO[(e - FC) * BB + b]);
      if (i >= 0) {
        union { ushort u[8]; uint4 v; } hv;
        hv.v = hfcIn[(size_t)g * BB + b];
        float a = 0.f;
#pragma unroll
        for (int c = 0; c < 8; c++) a += bf2f(hv.u[c]) * wsm3[es][c];
        rv += a;
      }
      xeO[(e - FC) * BB + b] = f2bf(rv);
    }
  }
}

// ---- output: out[b, 11000+j] = xeO[j][b] / 4 ----
__global__ void k_out(const ushort* __restrict__ xeO, float* __restrict__ out) {
  __shared__ float t[32][33];
  int j0 = blockIdx.x * 32, b0 = blockIdx.y * 32;
  int tx = threadIdx.x, ty = threadIdx.y;
#pragma unroll
  for (int s2 = 0; s2 < 4; s2++) {
    int j = j0 + ty + s2 * 8;
    if (j < 1000) t[ty + s2 * 8][tx] = bf2f(xeO[j * BB + b0 + tx]);
  }
  __syncthreads();
#pragma unroll
  for (int s2 = 0; s2 < 4; s2++) {
    int b = b0 + ty + s2 * 8;
    int j = j0 + tx;
    if (j < 1000) out[b * NN + 11000 + j] = t[tx][ty + s2 * 8] * 0.25f;
  }
}

extern "C" void kernel_launch(void* const* d_in, const int* in_sizes, int n_in,
                              void* d_out, int out_size, void* d_ws, size_t ws_size,
                              hipStream_t stream) {
  const float* x = (const float*)d_in[0];
  const float* W_ae1 = (const float*)d_in[1];
  const float* b_ae1 = (const float*)d_in[2];
  const float* W2 = (const float*)d_in[3];
  const float* b_ae2 = (const float*)d_in[4];
  const float* w1_vals = (const float*)d_in[5];
  const float* b1 = (const float*)d_in[6];
  const float* w3_vals = (const float*)d_in[7];
  const float* b3 = (const float*)d_in[8];
  const int* src = (const int*)d_in[9];
  const int* w3_cols = (const int*)d_in[14];

  int nnz3 = in_sizes[13];
  int n_fe = nnz3 / 8;

  // Workspace (f32 slot offsets); all uint4 regions 16B-aligned.
  float* W = (float*)d_ws;
  float* h_raw = W + 0;                   // 12,800  [k*128+b]
  float* red = W + 12800;                 // 256  (zeroed with h_raw in prep0)
  ushort* hbf = (ushort*)(W + 13056);     // 8,192 -> ends 21,248
  int* map = (int*)(W + 21248);           // 57,000 ints -> ends 78,248
  float* xT = W + 78400;                  // 1,536,000 -> ends 1,614,400
  uint4* xeF = (uint4*)(W + 1614400);     // 3,584,000 -> ends 5,198,400
  ushort* xeO = (ushort*)(W + 5198400);   // 64,000 -> ends 5,262,400
  uint4* zT4 = (uint4*)(W + 5262400);     // 3,584,000 -> ends 8,846,400
  uint4* hfcA = (uint4*)(W + 8846400);    // 3,584,000 -> ends 12,430,400
  uint4* hfcB = (uint4*)(W + 12430400);   // 3,584,000 -> ends 16,014,400
  ushort* w2m = (ushort*)(W + 16014400);  // 3,584,000 -> ends 19,598,400

  k_prep0<<<6774, 256, 0, stream>>>(x, xT, W2, w2m, map, (float*)d_out, h_raw);
  k_ae1<<<dim3(25, 80), 128, 0, stream>>>(xT, W_ae1, h_raw);
  k_prep1<<<4008 + (n_fe + 255) / 256, 256, 0, stream>>>(xT, src, xeF, xeO, h_raw,
                                                         b_ae1, hbf, w3_cols, map,
                                                         n_fe);
  k_ae2<<<875, 256, 0, stream>>>(hbf, w2m, b_ae2, (ushort*)zT4, red);
  k_layer1<<<NFN / 4, 256, 0, stream>>>(xeF, w1_vals, b1, zT4, red, hfcA);
  uint4* hin = hfcA;
  uint4* hout = hfcB;
  for (int l = 0; l < 4; l++) {
    int do_l1 = (l < 3) ? 1 : 0;
    k_fused<<<3750, 256, 0, stream>>>(hin, w3_vals + (size_t)l * nnz3,
                                      b3 + (size_t)l * EE, map, src, xeF, xeO,
                                      w1_vals + (size_t)(l + 1) * 448000 * (size_t)do_l1,
                                      b1 + (size_t)(l + 1) * FC * (size_t)do_l1,
                                      zT4, red, hout, do_l1);
    uint4* tmp = hin; hin = hout; hout = tmp;
  }
  k_out<<<dim3(32, 4), dim3(32, 8), 0, stream>>>(xeO, (float*)d_out);
}